// Round 8
// baseline (330.328 us; speedup 1.0000x reference)
//
#include <hip/hip_runtime.h>
#include <hip/hip_bf16.h>

#define D_MODEL 1024
#define NHEAD   16
#define HEAD_DIM 64
#define BATCH   2
#define SEQ     2048
#define NTOK    (BATCH*SEQ)   // 4096

// log2(10000)/64
#define FREQ_LOG2 0.20762050593046015f

typedef short  bfrag __attribute__((ext_vector_type(8)));  // 8 bf16 = 4 VGPR
typedef float  ffrag __attribute__((ext_vector_type(4)));  // C/D frag

__device__ inline ushort f2bf(float x) {
    __hip_bfloat16 h = __float2bfloat16(x);
    return __builtin_bit_cast(ushort, h);
}
__device__ inline void split_bf(float x, ushort& hi, ushort& lo) {
    __hip_bfloat16 h = __float2bfloat16(x);
    hi = __builtin_bit_cast(ushort, h);
    lo = f2bf(x - __bfloat162float(h));
}

// ---------------------------------------------------------------------------
// Pre-pass 1: split data -> Ahi, Alo  (bf16 hi/lo), [4096][1024]
// ---------------------------------------------------------------------------
__global__ __launch_bounds__(256)
void split_data(const float* __restrict__ x, ushort* __restrict__ hi,
                ushort* __restrict__ lo)
{
    const int i4 = (blockIdx.x * 256 + threadIdx.x) * 4;
    const float4 v = *(const float4*)(x + i4);
    ushort4 h, l;
    split_bf(v.x, h.x, l.x); split_bf(v.y, h.y, l.y);
    split_bf(v.z, h.z, l.z); split_bf(v.w, h.w, l.w);
    *(ushort4*)(hi + i4) = h;
    *(ushort4*)(lo + i4) = l;
}

// ---------------------------------------------------------------------------
// Pre-pass 2: W[k][n] -> WT[n][k], plain bf16.  grid (16,16,3)
// ---------------------------------------------------------------------------
__global__ __launch_bounds__(256)
void split_tr_w(const float* __restrict__ Wq, const float* __restrict__ Wk,
                const float* __restrict__ Wv, ushort* __restrict__ hi)
{
    const int z = blockIdx.z;
    const float* W = (z == 0) ? Wq : (z == 1) ? Wk : Wv;
    ushort* thi = hi + (size_t)z * D_MODEL * D_MODEL;

    __shared__ float T[64][65];
    const int t  = threadIdx.x;
    const int k0 = blockIdx.x * 64, n0 = blockIdx.y * 64;

    #pragma unroll
    for (int i = 0; i < 4; i++) {
        const int f = i * 256 + t, r = f >> 4, c = (f & 15) * 4;
        const float4 v = *(const float4*)(W + (size_t)(k0 + r) * D_MODEL + n0 + c);
        T[r][c] = v.x; T[r][c + 1] = v.y; T[r][c + 2] = v.z; T[r][c + 3] = v.w;
    }
    __syncthreads();
    #pragma unroll
    for (int i = 0; i < 4; i++) {
        const int f = i * 256 + t, nr = f >> 4, kc = (f & 15) * 4;
        ushort4 h;
        h.x = f2bf(T[kc + 0][nr]);
        h.y = f2bf(T[kc + 1][nr]);
        h.z = f2bf(T[kc + 2][nr]);
        h.w = f2bf(T[kc + 3][nr]);
        const size_t o = (size_t)(n0 + nr) * D_MODEL + k0 + kc;
        *(ushort4*)(thi + o) = h;
    }
}

// ---------------------------------------------------------------------------
// Kernel 3: bf16x2 GEMM 128x128xBK32 + bias + RoPE epilogue. (R7 geometry)
// z=0 -> Q hi/lo (pre-scaled 1/8); z=1 -> K hi only; z=2 -> VT bf16.
// ---------------------------------------------------------------------------
#define ALD 40   // LDS stride (elems): rows 80B apart

union GemmSM {
    struct { ushort ahi[128 * ALD], alo[128 * ALD], bhi[128 * ALD]; } st;
    float c[64 * 132];
};

__global__ __launch_bounds__(256, 3)
void gemm_qkv(const ushort* __restrict__ Ahi, const ushort* __restrict__ Alo,
              const ushort* __restrict__ WThi,
              const float* __restrict__ bq, const float* __restrict__ bk,
              const float* __restrict__ bv, const float* __restrict__ temporal,
              ushort* __restrict__ Qhi, ushort* __restrict__ Qlo,
              ushort* __restrict__ Khi,
              ushort* __restrict__ VT)
{
    __shared__ GemmSM sm;
    const int z  = blockIdx.z;
    const int m0 = blockIdx.x * 128;
    const int n0 = blockIdx.y * 128;
    const float* bias = (z == 0) ? bq : (z == 1) ? bk : bv;
    const ushort* Bh = WThi + (size_t)z * D_MODEL * D_MODEL;

    const int t = threadIdx.x;
    const int w = t >> 6, lane = t & 63;
    const int lane15 = lane & 15, quad8 = (lane >> 4) * 8, quad = lane >> 4;
    const int wm = (w >> 1) * 64, wn = (w & 1) * 64;

    ffrag acc[4][4];
    #pragma unroll
    for (int i = 0; i < 4; i++)
        #pragma unroll
        for (int j = 0; j < 4; j++) acc[i][j] = (ffrag){0.f, 0.f, 0.f, 0.f};

    const int r1 = t >> 2,            c1 = (t & 3) * 8;
    const int r2 = (t + 256) >> 2,    c2 = ((t + 256) & 3) * 8;

    for (int k0 = 0; k0 < D_MODEL; k0 += 32) {
        const int4 a0 = *(const int4*)(Ahi + (size_t)(m0 + r1) * D_MODEL + k0 + c1);
        const int4 a1 = *(const int4*)(Ahi + (size_t)(m0 + r2) * D_MODEL + k0 + c2);
        const int4 l0 = *(const int4*)(Alo + (size_t)(m0 + r1) * D_MODEL + k0 + c1);
        const int4 l1 = *(const int4*)(Alo + (size_t)(m0 + r2) * D_MODEL + k0 + c2);
        const int4 b0 = *(const int4*)(Bh  + (size_t)(n0 + r1) * D_MODEL + k0 + c1);
        const int4 b1 = *(const int4*)(Bh  + (size_t)(n0 + r2) * D_MODEL + k0 + c2);
        *(int4*)&sm.st.ahi[r1 * ALD + c1] = a0;  *(int4*)&sm.st.ahi[r2 * ALD + c2] = a1;
        *(int4*)&sm.st.alo[r1 * ALD + c1] = l0;  *(int4*)&sm.st.alo[r2 * ALD + c2] = l1;
        *(int4*)&sm.st.bhi[r1 * ALD + c1] = b0;  *(int4*)&sm.st.bhi[r2 * ALD + c2] = b1;
        __syncthreads();

        bfrag ah[4], al[4];
        #pragma unroll
        for (int mt = 0; mt < 4; mt++) {
            ah[mt] = *(const bfrag*)&sm.st.ahi[(wm + mt * 16 + lane15) * ALD + quad8];
            al[mt] = *(const bfrag*)&sm.st.alo[(wm + mt * 16 + lane15) * ALD + quad8];
        }
        #pragma unroll
        for (int nt = 0; nt < 4; nt++) {
            const bfrag bh = *(const bfrag*)&sm.st.bhi[(wn + nt * 16 + lane15) * ALD + quad8];
            #pragma unroll
            for (int mt = 0; mt < 4; mt++) {
                ffrag a = acc[mt][nt];
                a = __builtin_amdgcn_mfma_f32_16x16x32_bf16(ah[mt], bh, a, 0, 0, 0);
                a = __builtin_amdgcn_mfma_f32_16x16x32_bf16(al[mt], bh, a, 0, 0, 0);
                acc[mt][nt] = a;
            }
        }
        __syncthreads();
    }

    float bn[4];
    #pragma unroll
    for (int nt = 0; nt < 4; nt++) bn[nt] = bias[n0 + wn + nt * 16 + lane15];

    const int CST = (z == 2) ? 129 : 132;

    #pragma unroll
    for (int p = 0; p < 2; p++) {
        if (p) __syncthreads();
        if ((w >> 1) == p) {
            #pragma unroll
            for (int mt = 0; mt < 4; mt++)
                #pragma unroll
                for (int nt = 0; nt < 4; nt++)
                    #pragma unroll
                    for (int rr = 0; rr < 4; rr++)
                        sm.c[(mt * 16 + quad * 4 + rr) * CST + wn + nt * 16 + lane15] =
                            acc[mt][nt][rr] + bn[nt];
        }
        __syncthreads();

        if (z < 2) {
            ushort* ohi = (z == 0) ? Qhi : Khi;
            const float sc = (z == 0) ? 0.125f : 1.0f;
            #pragma unroll
            for (int i = 0; i < 8; i++) {
                const int f = i * 256 + t, r = f >> 5, c4 = (f & 31) * 4;
                float4 v = *(float4*)&sm.c[r * 132 + c4];
                const int m = m0 + p * 64 + r;
                const float tv = temporal[m];
                const float fr0 = exp2f(-(float)(c4 & 63) * FREQ_LOG2);
                const float fr1 = exp2f(-(float)((c4 + 2) & 63) * FREQ_LOG2);
                float s0, c0, s1, c1v;
                __sincosf(tv * fr0, &s0, &c0);
                __sincosf(tv * fr1, &s1, &c1v);
                const float y0 = (v.x * c0 - v.y * s0) * sc;
                const float y1 = (v.y * c0 + v.x * s0) * sc;
                const float y2 = (v.z * c1v - v.w * s1) * sc;
                const float y3 = (v.w * c1v + v.z * s1) * sc;
                ushort4 h, l;
                split_bf(y0, h.x, l.x); split_bf(y1, h.y, l.y);
                split_bf(y2, h.z, l.z); split_bf(y3, h.w, l.w);
                const size_t o = (size_t)m * D_MODEL + n0 + c4;
                *(ushort4*)(ohi + o) = h;
                if (z == 0) *(ushort4*)(Qlo + o) = l;   // K needs no lo
            }
        } else {
            const int bb = m0 >> 11;
            #pragma unroll
            for (int i = 0; i < 4; i++) {
                const int cid = i * 256 + t, col = cid >> 3, tg = (cid & 7) * 8;
                ushort u8[8];
                #pragma unroll
                for (int j = 0; j < 8; j++) u8[j] = f2bf(sm.c[(tg + j) * 129 + col]);
                const int ncol = n0 + col, hh = ncol >> 6, d = ncol & 63;
                const size_t dst = ((size_t)(bb * NHEAD + hh) * HEAD_DIM + d) * SEQ +
                                   (m0 & (SEQ - 1)) + p * 64 + tg;
                *(int4*)(VT + dst) = *(int4*)u8;
            }
        }
    }
}

// ---------------------------------------------------------------------------
// Kernel 4: MFMA flash attention, streaming softmax, 128-q-row tile.
// Block = 128 q-rows of one (b,h); wave w owns rows {w*16..}+{64+w*16..}.
// K plain bf16 (QK = qh*k + ql*k); each staged K/V tile feeds 2x MFMA work
// vs R7 (barrier count and K/V L2 traffic per FLOP halved).
// ---------------------------------------------------------------------------
#define KLD 72   // rows 144B apart -> banks +4 mod 32

__global__ __launch_bounds__(256, 2)
void attn_mfma(const ushort* __restrict__ Qhi, const ushort* __restrict__ Qlo,
               const ushort* __restrict__ Khi,
               const ushort* __restrict__ VT,  const float* __restrict__ mask,
               float* __restrict__ out)
{
    __shared__ ushort lsK[64 * KLD], lsV[64 * KLD], lsP[128 * KLD];

    // 512 blocks: xcd = bid&7, qb = (bid>>3)&15, bhHigh = bid>>7 (0..3)
    const int bid = blockIdx.x;
    const int bh  = (bid & 7) * 4 + (bid >> 7);
    const int qb  = (bid >> 3) & 15;
    const int b   = bh >> 4, h = bh & 15;
    const int q0  = qb * 128;

    const int t = threadIdx.x, w = t >> 6, lane = t & 63;
    const int lane15 = lane & 15, quad = lane >> 4, quad8 = quad * 8;
    const size_t tok0 = (size_t)b * SEQ;

    // loop-invariant Q fragments (A-layout), 2 row-groups x 2 k-halves
    bfrag qh[2][2], ql[2][2];
    #pragma unroll
    for (int mi = 0; mi < 2; mi++) {
        const size_t qrow = (tok0 + q0 + mi * 64 + w * 16 + lane15) * D_MODEL + h * HEAD_DIM;
        #pragma unroll
        for (int ks = 0; ks < 2; ks++) {
            qh[mi][ks] = *(const bfrag*)(Qhi + qrow + ks * 32 + quad8);
            ql[mi][ks] = *(const bfrag*)(Qlo + qrow + ks * 32 + quad8);
        }
    }

    ffrag of[2][4];
    float l_i[2][4];
    #pragma unroll
    for (int mi = 0; mi < 2; mi++)
        #pragma unroll
        for (int nt = 0; nt < 4; nt++) {
            of[mi][nt] = (ffrag){0.f, 0.f, 0.f, 0.f};
            l_i[mi][nt] = 0.f;   // [mi][rr] reuse
        }

    // staging: 2 chunks/thread per array
    const int r1 = t >> 3,      c1 = (t & 7) * 8;
    const int r2 = 32 + r1,     c2 = c1;
    const ushort* Kh0 = Khi + tok0 * D_MODEL + h * HEAD_DIM;
    const ushort* Vt0 = VT + (size_t)(b * NHEAD + h) * HEAD_DIM * SEQ;

    int4 pk0 = *(const int4*)(Kh0 + (size_t)r1 * D_MODEL + c1);
    int4 pk1 = *(const int4*)(Kh0 + (size_t)r2 * D_MODEL + c2);
    int4 pv0 = *(const int4*)(Vt0 + (size_t)r1 * SEQ + c1);
    int4 pv1 = *(const int4*)(Vt0 + (size_t)r2 * SEQ + c2);

    const float* mrow0 = mask + (size_t)(q0 + w * 16 + quad * 4) * SEQ;

    for (int kt = 0; kt < SEQ; kt += 64) {
        *(int4*)&lsK[r1 * KLD + c1] = pk0;  *(int4*)&lsK[r2 * KLD + c2] = pk1;
        *(int4*)&lsV[r1 * KLD + c1] = pv0;  *(int4*)&lsV[r2 * KLD + c2] = pv1;
        __syncthreads();

        const int ktn = (kt + 64 < SEQ) ? kt + 64 : 0;
        pk0 = *(const int4*)(Kh0 + (size_t)(ktn + r1) * D_MODEL + c1);
        pk1 = *(const int4*)(Kh0 + (size_t)(ktn + r2) * D_MODEL + c2);
        pv0 = *(const int4*)(Vt0 + (size_t)r1 * SEQ + ktn + c1);
        pv1 = *(const int4*)(Vt0 + (size_t)r2 * SEQ + ktn + c2);

        // mask loads (overlap MFMAs)
        float mv[2][4][4];
        #pragma unroll
        for (int mi = 0; mi < 2; mi++)
            #pragma unroll
            for (int nt = 0; nt < 4; nt++)
                #pragma unroll
                for (int rr = 0; rr < 4; rr++)
                    mv[mi][nt][rr] = mrow0[(size_t)(mi * 64 + rr) * SEQ + kt + nt * 16 + lane15];

        // S = (Q/8) K^T  (qh + ql) x k
        ffrag s[2][4];
        #pragma unroll
        for (int nt = 0; nt < 4; nt++) {
            bfrag kf[2];
            #pragma unroll
            for (int ks = 0; ks < 2; ks++)
                kf[ks] = *(const bfrag*)&lsK[(nt * 16 + lane15) * KLD + ks * 32 + quad8];
            #pragma unroll
            for (int mi = 0; mi < 2; mi++) {
                ffrag a = (ffrag){0.f, 0.f, 0.f, 0.f};
                #pragma unroll
                for (int ks = 0; ks < 2; ks++) {
                    a = __builtin_amdgcn_mfma_f32_16x16x32_bf16(qh[mi][ks], kf[ks], a, 0, 0, 0);
                    a = __builtin_amdgcn_mfma_f32_16x16x32_bf16(ql[mi][ks], kf[ks], a, 0, 0, 0);
                }
                s[mi][nt] = a;
            }
        }

        // streaming softmax: exp, per-lane l partials, P^T to LDS (bf16)
        #pragma unroll
        for (int mi = 0; mi < 2; mi++)
            #pragma unroll
            for (int nt = 0; nt < 4; nt++)
                #pragma unroll
                for (int rr = 0; rr < 4; rr++) {
                    const float e = __expf(s[mi][nt][rr] + mv[mi][nt][rr]);
                    l_i[mi][rr] += e;
                    lsP[(mi * 64 + w * 16 + quad * 4 + rr) * KLD + nt * 16 + lane15] = f2bf(e);
                }

        // O += P V  (P rows are wave-private: no barrier)
        #pragma unroll
        for (int mi = 0; mi < 2; mi++)
            #pragma unroll
            for (int ks = 0; ks < 2; ks++) {
                const bfrag pf = *(const bfrag*)&lsP[(mi * 64 + w * 16 + lane15) * KLD + ks * 32 + quad8];
                #pragma unroll
                for (int nt = 0; nt < 4; nt++) {
                    const bfrag vf = *(const bfrag*)&lsV[(nt * 16 + lane15) * KLD + ks * 32 + quad8];
                    of[mi][nt] = __builtin_amdgcn_mfma_f32_16x16x32_bf16(pf, vf, of[mi][nt], 0, 0, 0);
                }
            }
        __syncthreads();
    }

    #pragma unroll
    for (int mi = 0; mi < 2; mi++) {
        float inv[4];
        #pragma unroll
        for (int rr = 0; rr < 4; rr++) {
            float v = l_i[mi][rr];
            #pragma unroll
            for (int off = 1; off < 16; off <<= 1) v += __shfl_xor(v, off);
            inv[rr] = 1.0f / v;
        }
        #pragma unroll
        for (int nt = 0; nt < 4; nt++)
            #pragma unroll
            for (int rr = 0; rr < 4; rr++)
                out[(tok0 + q0 + mi * 64 + w * 16 + quad * 4 + rr) * D_MODEL +
                    h * HEAD_DIM + nt * 16 + lane15] = of[mi][nt][rr] * inv[rr];
    }
}

// ---------------------------------------------------------------------------
extern "C" void kernel_launch(void* const* d_in, const int* in_sizes, int n_in,
                              void* d_out, int out_size, void* d_ws, size_t ws_size,
                              hipStream_t stream)
{
    const float* data     = (const float*)d_in[0];
    const float* temporal = (const float*)d_in[1];
    const float* mask     = (const float*)d_in[2];
    const float* Wq = (const float*)d_in[3];
    const float* bq = (const float*)d_in[4];
    const float* Wk = (const float*)d_in[5];
    const float* bk = (const float*)d_in[6];
    const float* Wv = (const float*)d_in[7];
    const float* bv = (const float*)d_in[8];
    float* out = (float*)d_out;

    char* ws = (char*)d_ws;
    const size_t MB = 1024 * 1024;
    ushort* Ahi  = (ushort*)(ws + 0 * MB);
    ushort* Alo  = (ushort*)(ws + 8 * MB);
    ushort* WThi = (ushort*)(ws + 16 * MB);   // 6 MB (3x1024x1024 bf16)
    ushort* Qhi  = (ushort*)(ws + 28 * MB);
    ushort* Qlo  = (ushort*)(ws + 36 * MB);
    ushort* Khi  = (ushort*)(ws + 44 * MB);
    ushort* VT   = (ushort*)(ws + 60 * MB);

    split_data<<<dim3(NTOK * D_MODEL / 1024), 256, 0, stream>>>(data, Ahi, Alo);
    split_tr_w<<<dim3(16, 16, 3), 256, 0, stream>>>(Wq, Wk, Wv, WThi);
    gemm_qkv<<<dim3(NTOK / 128, D_MODEL / 128, 3), 256, 0, stream>>>(
        Ahi, Alo, WThi, bq, bk, bv, temporal,
        Qhi, Qlo, Khi, VT);
    attn_mfma<<<dim3(BATCH * NHEAD * SEQ / 128), 256, 0, stream>>>(
        Qhi, Qlo, Khi, VT, mask, out);
}

// Round 9
// 299.157 us; speedup vs baseline: 1.1042x; 1.1042x over previous
//
#include <hip/hip_runtime.h>
#include <hip/hip_bf16.h>

#define D_MODEL 1024
#define NHEAD   16
#define HEAD_DIM 64
#define BATCH   2
#define SEQ     2048
#define NTOK    (BATCH*SEQ)   // 4096

// log2(10000)/64
#define FREQ_LOG2 0.20762050593046015f

typedef short  bfrag __attribute__((ext_vector_type(8)));  // 8 bf16 = 4 VGPR
typedef float  ffrag __attribute__((ext_vector_type(4)));  // C/D frag

__device__ inline ushort f2bf(float x) {
    __hip_bfloat16 h = __float2bfloat16(x);
    return __builtin_bit_cast(ushort, h);
}
__device__ inline void split_bf(float x, ushort& hi, ushort& lo) {
    __hip_bfloat16 h = __float2bfloat16(x);
    hi = __builtin_bit_cast(ushort, h);
    lo = f2bf(x - __bfloat162float(h));
}

// ---------------------------------------------------------------------------
// Pre-pass 1: split data -> Ahi, Alo  (bf16 hi/lo), [4096][1024]
// ---------------------------------------------------------------------------
__global__ __launch_bounds__(256)
void split_data(const float* __restrict__ x, ushort* __restrict__ hi,
                ushort* __restrict__ lo)
{
    const int i4 = (blockIdx.x * 256 + threadIdx.x) * 4;
    const float4 v = *(const float4*)(x + i4);
    ushort4 h, l;
    split_bf(v.x, h.x, l.x); split_bf(v.y, h.y, l.y);
    split_bf(v.z, h.z, l.z); split_bf(v.w, h.w, l.w);
    *(ushort4*)(hi + i4) = h;
    *(ushort4*)(lo + i4) = l;
}

// ---------------------------------------------------------------------------
// Pre-pass 2: W[k][n] -> WT[n][k], plain bf16.  grid (16,16,3)
// ---------------------------------------------------------------------------
__global__ __launch_bounds__(256)
void split_tr_w(const float* __restrict__ Wq, const float* __restrict__ Wk,
                const float* __restrict__ Wv, ushort* __restrict__ hi)
{
    const int z = blockIdx.z;
    const float* W = (z == 0) ? Wq : (z == 1) ? Wk : Wv;
    ushort* thi = hi + (size_t)z * D_MODEL * D_MODEL;

    __shared__ float T[64][65];
    const int t  = threadIdx.x;
    const int k0 = blockIdx.x * 64, n0 = blockIdx.y * 64;

    #pragma unroll
    for (int i = 0; i < 4; i++) {
        const int f = i * 256 + t, r = f >> 4, c = (f & 15) * 4;
        const float4 v = *(const float4*)(W + (size_t)(k0 + r) * D_MODEL + n0 + c);
        T[r][c] = v.x; T[r][c + 1] = v.y; T[r][c + 2] = v.z; T[r][c + 3] = v.w;
    }
    __syncthreads();
    #pragma unroll
    for (int i = 0; i < 4; i++) {
        const int f = i * 256 + t, nr = f >> 4, kc = (f & 15) * 4;
        ushort4 h;
        h.x = f2bf(T[kc + 0][nr]);
        h.y = f2bf(T[kc + 1][nr]);
        h.z = f2bf(T[kc + 2][nr]);
        h.w = f2bf(T[kc + 3][nr]);
        const size_t o = (size_t)(n0 + nr) * D_MODEL + k0 + kc;
        *(ushort4*)(thi + o) = h;
    }
}

// ---------------------------------------------------------------------------
// Kernel 3: bf16x2 GEMM 128x128xBK32 + bias + RoPE epilogue. (R7 geometry)
// z=0 -> Q hi/lo (pre-scaled 1/8); z=1 -> K hi only; z=2 -> VT bf16.
// ---------------------------------------------------------------------------
#define ALD 40   // LDS stride (elems): rows 80B apart

union GemmSM {
    struct { ushort ahi[128 * ALD], alo[128 * ALD], bhi[128 * ALD]; } st;
    float c[64 * 132];
};

__global__ __launch_bounds__(256, 3)
void gemm_qkv(const ushort* __restrict__ Ahi, const ushort* __restrict__ Alo,
              const ushort* __restrict__ WThi,
              const float* __restrict__ bq, const float* __restrict__ bk,
              const float* __restrict__ bv, const float* __restrict__ temporal,
              ushort* __restrict__ Qhi, ushort* __restrict__ Qlo,
              ushort* __restrict__ Khi,
              ushort* __restrict__ VT)
{
    __shared__ GemmSM sm;
    const int z  = blockIdx.z;
    const int m0 = blockIdx.x * 128;
    const int n0 = blockIdx.y * 128;
    const float* bias = (z == 0) ? bq : (z == 1) ? bk : bv;
    const ushort* Bh = WThi + (size_t)z * D_MODEL * D_MODEL;

    const int t = threadIdx.x;
    const int w = t >> 6, lane = t & 63;
    const int lane15 = lane & 15, quad8 = (lane >> 4) * 8, quad = lane >> 4;
    const int wm = (w >> 1) * 64, wn = (w & 1) * 64;

    ffrag acc[4][4];
    #pragma unroll
    for (int i = 0; i < 4; i++)
        #pragma unroll
        for (int j = 0; j < 4; j++) acc[i][j] = (ffrag){0.f, 0.f, 0.f, 0.f};

    const int r1 = t >> 2,            c1 = (t & 3) * 8;
    const int r2 = (t + 256) >> 2,    c2 = ((t + 256) & 3) * 8;

    for (int k0 = 0; k0 < D_MODEL; k0 += 32) {
        const int4 a0 = *(const int4*)(Ahi + (size_t)(m0 + r1) * D_MODEL + k0 + c1);
        const int4 a1 = *(const int4*)(Ahi + (size_t)(m0 + r2) * D_MODEL + k0 + c2);
        const int4 l0 = *(const int4*)(Alo + (size_t)(m0 + r1) * D_MODEL + k0 + c1);
        const int4 l1 = *(const int4*)(Alo + (size_t)(m0 + r2) * D_MODEL + k0 + c2);
        const int4 b0 = *(const int4*)(Bh  + (size_t)(n0 + r1) * D_MODEL + k0 + c1);
        const int4 b1 = *(const int4*)(Bh  + (size_t)(n0 + r2) * D_MODEL + k0 + c2);
        *(int4*)&sm.st.ahi[r1 * ALD + c1] = a0;  *(int4*)&sm.st.ahi[r2 * ALD + c2] = a1;
        *(int4*)&sm.st.alo[r1 * ALD + c1] = l0;  *(int4*)&sm.st.alo[r2 * ALD + c2] = l1;
        *(int4*)&sm.st.bhi[r1 * ALD + c1] = b0;  *(int4*)&sm.st.bhi[r2 * ALD + c2] = b1;
        __syncthreads();

        bfrag ah[4], al[4];
        #pragma unroll
        for (int mt = 0; mt < 4; mt++) {
            ah[mt] = *(const bfrag*)&sm.st.ahi[(wm + mt * 16 + lane15) * ALD + quad8];
            al[mt] = *(const bfrag*)&sm.st.alo[(wm + mt * 16 + lane15) * ALD + quad8];
        }
        #pragma unroll
        for (int nt = 0; nt < 4; nt++) {
            const bfrag bh = *(const bfrag*)&sm.st.bhi[(wn + nt * 16 + lane15) * ALD + quad8];
            #pragma unroll
            for (int mt = 0; mt < 4; mt++) {
                ffrag a = acc[mt][nt];
                a = __builtin_amdgcn_mfma_f32_16x16x32_bf16(ah[mt], bh, a, 0, 0, 0);
                a = __builtin_amdgcn_mfma_f32_16x16x32_bf16(al[mt], bh, a, 0, 0, 0);
                acc[mt][nt] = a;
            }
        }
        __syncthreads();
    }

    float bn[4];
    #pragma unroll
    for (int nt = 0; nt < 4; nt++) bn[nt] = bias[n0 + wn + nt * 16 + lane15];

    const int CST = (z == 2) ? 129 : 132;

    #pragma unroll
    for (int p = 0; p < 2; p++) {
        if (p) __syncthreads();
        if ((w >> 1) == p) {
            #pragma unroll
            for (int mt = 0; mt < 4; mt++)
                #pragma unroll
                for (int nt = 0; nt < 4; nt++)
                    #pragma unroll
                    for (int rr = 0; rr < 4; rr++)
                        sm.c[(mt * 16 + quad * 4 + rr) * CST + wn + nt * 16 + lane15] =
                            acc[mt][nt][rr] + bn[nt];
        }
        __syncthreads();

        if (z < 2) {
            ushort* ohi = (z == 0) ? Qhi : Khi;
            const float sc = (z == 0) ? 0.125f : 1.0f;
            #pragma unroll
            for (int i = 0; i < 8; i++) {
                const int f = i * 256 + t, r = f >> 5, c4 = (f & 31) * 4;
                float4 v = *(float4*)&sm.c[r * 132 + c4];
                const int m = m0 + p * 64 + r;
                const float tv = temporal[m];
                const float fr0 = exp2f(-(float)(c4 & 63) * FREQ_LOG2);
                const float fr1 = exp2f(-(float)((c4 + 2) & 63) * FREQ_LOG2);
                float s0, c0, s1, c1v;
                __sincosf(tv * fr0, &s0, &c0);
                __sincosf(tv * fr1, &s1, &c1v);
                const float y0 = (v.x * c0 - v.y * s0) * sc;
                const float y1 = (v.y * c0 + v.x * s0) * sc;
                const float y2 = (v.z * c1v - v.w * s1) * sc;
                const float y3 = (v.w * c1v + v.z * s1) * sc;
                ushort4 h, l;
                split_bf(y0, h.x, l.x); split_bf(y1, h.y, l.y);
                split_bf(y2, h.z, l.z); split_bf(y3, h.w, l.w);
                const size_t o = (size_t)m * D_MODEL + n0 + c4;
                *(ushort4*)(ohi + o) = h;
                if (z == 0) *(ushort4*)(Qlo + o) = l;   // K needs no lo
            }
        } else {
            const int bb = m0 >> 11;
            #pragma unroll
            for (int i = 0; i < 4; i++) {
                const int cid = i * 256 + t, col = cid >> 3, tg = (cid & 7) * 8;
                ushort u8[8];
                #pragma unroll
                for (int j = 0; j < 8; j++) u8[j] = f2bf(sm.c[(tg + j) * 129 + col]);
                const int ncol = n0 + col, hh = ncol >> 6, d = ncol & 63;
                const size_t dst = ((size_t)(bb * NHEAD + hh) * HEAD_DIM + d) * SEQ +
                                   (m0 & (SEQ - 1)) + p * 64 + tg;
                *(int4*)(VT + dst) = *(int4*)u8;
            }
        }
    }
}

// ---------------------------------------------------------------------------
// Kernel 4: MFMA flash attention, streaming softmax, 64-q-row tile (R7
// geometry: 1024 blocks = 4/CU) with K plain bf16 (Q hi/lo): 16 S-MFMAs +
// 8 PV per tile per wave. LDS 3 arrays = 27.6 KB.
// ---------------------------------------------------------------------------
#define KLD 72   // rows 144B apart -> banks +4 mod 32

__global__ __launch_bounds__(256, 4)
void attn_mfma(const ushort* __restrict__ Qhi, const ushort* __restrict__ Qlo,
               const ushort* __restrict__ Khi,
               const ushort* __restrict__ VT,  const float* __restrict__ mask,
               float* __restrict__ out)
{
    __shared__ ushort lsK[64 * KLD], lsV[64 * KLD], lsP[64 * KLD];

    // XCD-L2 swizzle: blocks sharing one (b,h) K/V slab land on one XCD
    const int bid  = blockIdx.x;
    const int bh   = (bid & 7) * 4 + (bid >> 8);
    const int qb   = (bid >> 3) & 31;
    const int b    = bh >> 4, h = bh & 15;
    const int q0   = qb * 64;

    const int t = threadIdx.x, w = t >> 6, lane = t & 63;
    const int lane15 = lane & 15, quad = lane >> 4, quad8 = quad * 8;
    const size_t tok0 = (size_t)b * SEQ;

    // loop-invariant Q fragments (A-layout) straight from global
    bfrag qh[2], ql[2];
    const size_t qrow = (tok0 + q0 + w * 16 + lane15) * D_MODEL + h * HEAD_DIM;
    #pragma unroll
    for (int ks = 0; ks < 2; ks++) {
        qh[ks] = *(const bfrag*)(Qhi + qrow + ks * 32 + quad8);
        ql[ks] = *(const bfrag*)(Qlo + qrow + ks * 32 + quad8);
    }

    ffrag of[4];
    #pragma unroll
    for (int nt = 0; nt < 4; nt++) of[nt] = (ffrag){0.f, 0.f, 0.f, 0.f};
    float l_i[4] = {0.f, 0.f, 0.f, 0.f};

    // staging: 2 chunks/thread per array (rows 0..31 and 32..63)
    const int r1 = t >> 3,    c1 = (t & 7) * 8;
    const int r2 = 32 + r1,   c2 = c1;
    const ushort* Kh0 = Khi + tok0 * D_MODEL + h * HEAD_DIM;
    const ushort* Vt0 = VT + (size_t)(b * NHEAD + h) * HEAD_DIM * SEQ;

    int4 pk0 = *(const int4*)(Kh0 + (size_t)r1 * D_MODEL + c1);
    int4 pk1 = *(const int4*)(Kh0 + (size_t)r2 * D_MODEL + c2);
    int4 pv0 = *(const int4*)(Vt0 + (size_t)r1 * SEQ + c1);
    int4 pv1 = *(const int4*)(Vt0 + (size_t)r2 * SEQ + c2);

    const float* mrow = mask + (size_t)(q0 + w * 16 + quad * 4) * SEQ;

    for (int kt = 0; kt < SEQ; kt += 64) {
        *(int4*)&lsK[r1 * KLD + c1] = pk0;  *(int4*)&lsK[r2 * KLD + c2] = pk1;
        *(int4*)&lsV[r1 * KLD + c1] = pv0;  *(int4*)&lsV[r2 * KLD + c2] = pv1;
        __syncthreads();

        const int ktn = (kt + 64 < SEQ) ? kt + 64 : 0;
        pk0 = *(const int4*)(Kh0 + (size_t)(ktn + r1) * D_MODEL + c1);
        pk1 = *(const int4*)(Kh0 + (size_t)(ktn + r2) * D_MODEL + c2);
        pv0 = *(const int4*)(Vt0 + (size_t)r1 * SEQ + ktn + c1);
        pv1 = *(const int4*)(Vt0 + (size_t)r2 * SEQ + ktn + c2);

        // mask loads (overlap the MFMAs below)
        float mv[4][4];
        #pragma unroll
        for (int nt = 0; nt < 4; nt++)
            #pragma unroll
            for (int rr = 0; rr < 4; rr++)
                mv[nt][rr] = mrow[(size_t)rr * SEQ + kt + nt * 16 + lane15];

        // S = (Q/8) K^T  (qh + ql) x k
        ffrag s[4];
        #pragma unroll
        for (int nt = 0; nt < 4; nt++) {
            ffrag a = (ffrag){0.f, 0.f, 0.f, 0.f};
            #pragma unroll
            for (int ks = 0; ks < 2; ks++) {
                const bfrag kf = *(const bfrag*)&lsK[(nt * 16 + lane15) * KLD + ks * 32 + quad8];
                a = __builtin_amdgcn_mfma_f32_16x16x32_bf16(qh[ks], kf, a, 0, 0, 0);
                a = __builtin_amdgcn_mfma_f32_16x16x32_bf16(ql[ks], kf, a, 0, 0, 0);
            }
            s[nt] = a;
        }

        // streaming softmax: exp, per-lane l partials, P^T to LDS (bf16)
        #pragma unroll
        for (int nt = 0; nt < 4; nt++) {
            #pragma unroll
            for (int rr = 0; rr < 4; rr++) {
                const float e = __expf(s[nt][rr] + mv[nt][rr]);
                l_i[rr] += e;
                lsP[(w * 16 + quad * 4 + rr) * KLD + nt * 16 + lane15] = f2bf(e);
            }
        }

        // O += P V  (P rows are wave-private: no barrier)
        #pragma unroll
        for (int ks = 0; ks < 2; ks++) {
            const bfrag pf = *(const bfrag*)&lsP[(w * 16 + lane15) * KLD + ks * 32 + quad8];
            #pragma unroll
            for (int nt = 0; nt < 4; nt++) {
                const bfrag vf = *(const bfrag*)&lsV[(nt * 16 + lane15) * KLD + ks * 32 + quad8];
                of[nt] = __builtin_amdgcn_mfma_f32_16x16x32_bf16(pf, vf, of[nt], 0, 0, 0);
            }
        }
        __syncthreads();
    }

    float inv[4];
    #pragma unroll
    for (int rr = 0; rr < 4; rr++) {
        float v = l_i[rr];
        #pragma unroll
        for (int off = 1; off < 16; off <<= 1) v += __shfl_xor(v, off);
        inv[rr] = 1.0f / v;
    }
    #pragma unroll
    for (int nt = 0; nt < 4; nt++)
        #pragma unroll
        for (int rr = 0; rr < 4; rr++)
            out[(tok0 + q0 + w * 16 + quad * 4 + rr) * D_MODEL + h * HEAD_DIM +
                nt * 16 + lane15] = of[nt][rr] * inv[rr];
}

// ---------------------------------------------------------------------------
extern "C" void kernel_launch(void* const* d_in, const int* in_sizes, int n_in,
                              void* d_out, int out_size, void* d_ws, size_t ws_size,
                              hipStream_t stream)
{
    const float* data     = (const float*)d_in[0];
    const float* temporal = (const float*)d_in[1];
    const float* mask     = (const float*)d_in[2];
    const float* Wq = (const float*)d_in[3];
    const float* bq = (const float*)d_in[4];
    const float* Wk = (const float*)d_in[5];
    const float* bk = (const float*)d_in[6];
    const float* Wv = (const float*)d_in[7];
    const float* bv = (const float*)d_in[8];
    float* out = (float*)d_out;

    char* ws = (char*)d_ws;
    const size_t MB = 1024 * 1024;
    ushort* Ahi  = (ushort*)(ws + 0 * MB);
    ushort* Alo  = (ushort*)(ws + 8 * MB);
    ushort* WThi = (ushort*)(ws + 16 * MB);   // 6 MB (3x1024x1024 bf16)
    ushort* Qhi  = (ushort*)(ws + 28 * MB);
    ushort* Qlo  = (ushort*)(ws + 36 * MB);
    ushort* Khi  = (ushort*)(ws + 44 * MB);
    ushort* VT   = (ushort*)(ws + 60 * MB);

    split_data<<<dim3(NTOK * D_MODEL / 1024), 256, 0, stream>>>(data, Ahi, Alo);
    split_tr_w<<<dim3(16, 16, 3), 256, 0, stream>>>(Wq, Wk, Wv, WThi);
    gemm_qkv<<<dim3(NTOK / 128, D_MODEL / 128, 3), 256, 0, stream>>>(
        Ahi, Alo, WThi, bq, bk, bv, temporal,
        Qhi, Qlo, Khi, VT);
    attn_mfma<<<dim3(BATCH * NHEAD * SEQ / 64), 256, 0, stream>>>(
        Qhi, Qlo, Khi, VT, mask, out);
}